// Round 9
// baseline (128.657 us; speedup 1.0000x reference)
//
#include <hip/hip_runtime.h>
#include <stdint.h>

// Problem constants (fixed by reference: scores (4, 131072) f32, m=4096, tau=1)
#define BROWS 4
#define NCOLS 131072           // 2^17
#define MREF  4096
#define HIST_BITS 13
#define NBUCK (1 << HIST_BITS) // 8192
#define USHIFT (32 - HIST_BITS)
#define HIST_BLK_PER_ROW 8
#define NPART 32
#define PQUOTA 192             // quota spacing (R8-proven: max partition < 1024)
#define PARTCAP 1024           // fixed bitonic size

__device__ __forceinline__ uint32_t orderable(float f) {
    uint32_t u = __float_as_uint(f);
    return (u & 0x80000000u) ? ~u : (u | 0x80000000u);
}
__device__ __forceinline__ float unorderable(uint32_t u) {
    uint32_t b = (u & 0x80000000u) ? (u & 0x7FFFFFFFu) : ~u;
    return __uint_as_float(b);
}

// Per-block private histograms, plain-stored to slots (no zeroing, no atomics
// at flush). 8 blocks/row over 16384-element chunks.
__global__ void k_hist(const float* __restrict__ sc, uint32_t* __restrict__ hslot) {
    __shared__ uint32_t h[NBUCK]; // 32 KiB
    for (int t = threadIdx.x; t < NBUCK; t += blockDim.x) h[t] = 0u;
    __syncthreads();
    int row  = blockIdx.x / HIST_BLK_PER_ROW;
    int part = blockIdx.x % HIST_BLK_PER_ROW;
    const int CHUNK = NCOLS / HIST_BLK_PER_ROW; // 16384
    const float* p = sc + row * NCOLS + part * CHUNK;
    for (int c = threadIdx.x; c < CHUNK; c += blockDim.x) {
        uint32_t u = orderable(p[c]);
        atomicAdd(&h[u >> USHIFT], 1u);
    }
    __syncthreads();
    uint32_t* g = hslot + ((size_t)(row * HIST_BLK_PER_ROW + part)) * NBUCK;
    for (int t = threadIdx.x; t < NBUCK; t += blockDim.x) g[t] = h[t];
}

// One block per row: sum 8 slots into LDS hist, then the R8-proven presum +
// thread-0 quota walk. Writes Bs[NPART+1] (bucket boundaries) and
// pse[NPART+1] (partition start offsets).
__global__ void k_thresh(const uint32_t* __restrict__ hslot, uint32_t* __restrict__ Hrow,
                         int* __restrict__ Bs, uint32_t* __restrict__ pse) {
    __shared__ uint32_t h[NBUCK]; // 32 KiB summed histogram
    __shared__ uint32_t part[256];
    int row = blockIdx.x;
    const uint32_t* basep = hslot + (size_t)row * HIST_BLK_PER_ROW * NBUCK;
    for (int t = threadIdx.x; t < NBUCK; t += blockDim.x) {
        uint32_t s = 0;
        for (int sl = 0; sl < HIST_BLK_PER_ROW; ++sl) s += basep[sl * NBUCK + t];
        h[t] = s;
    }
    __syncthreads();
    int bhi = NBUCK - 1 - (int)threadIdx.x * 32;
    uint32_t run = 0;
    for (int k = 0; k < 32; ++k) run += h[bhi - k];
    part[threadIdx.x] = run;
    __syncthreads();
    if (threadIdx.x == 0) {
        int      Bloc[NPART];
        uint32_t Ploc[NPART];
        for (int p = 0; p < NPART; ++p) { Bloc[p] = -1; Ploc[p] = 0u; }
        uint32_t cum = 0, T = 0;
        int H = 0, pi = 1;
        bool done = false;
        for (int t = 0; t < 256 && !done; ++t) {
            uint32_t cafter = cum + part[t];
            bool cross = (cafter >= (uint32_t)MREF) ||
                         (pi < NPART && cafter >= (uint32_t)(pi * PQUOTA));
            if (cross) {
                int tp = NBUCK - 1 - t * 32;
                for (int k2 = 0; k2 < 32 && !done; ++k2) {
                    int b = tp - k2;
                    uint32_t prev = cum;
                    cum += h[b];
                    while (pi < NPART && cum >= (uint32_t)(pi * PQUOTA)) {
                        Bloc[pi] = b; Ploc[pi] = prev; ++pi;
                    }
                    if (cum >= (uint32_t)MREF) { H = b; T = cum; done = true; }
                }
            } else {
                cum = cafter;
            }
        }
        for (int p = pi; p < NPART; ++p) { Bloc[p] = H - 1; Ploc[p] = T; }
        Hrow[row] = (uint32_t)H;
        Bs[row * (NPART + 1) + 0] = NBUCK; // sentinel upper bound
        for (int p = 1; p < NPART; ++p) Bs[row * (NPART + 1) + p] = Bloc[p];
        Bs[row * (NPART + 1) + NPART] = H - 1; // exclusive lower bound of last part
        for (int p = 0; p < NPART; ++p) pse[row * (NPART + 1) + p] = Ploc[p];
        pse[row * (NPART + 1) + NPART] = T;
    }
}

// 128 blocks = 4 rows x 32 partitions. Each block re-scans its row (L2-resident),
// keeps elements with bucket in (Bs[pp+1], Bs[pp]], LDS-appends, pads, sorts
// with the fixed P=1024 bitonic, and writes its slice of rv/ri.
__global__ void k_psort(const float* __restrict__ sc, const int* __restrict__ Bs,
                        const uint32_t* __restrict__ pse,
                        float* __restrict__ rv, uint32_t* __restrict__ ri) {
    __shared__ uint64_t lds[PARTCAP]; // 8 KiB
    __shared__ uint32_t cnt;
    int row = blockIdx.x >> 5;
    int pp  = blockIdx.x & 31;
    int hi = Bs[row * (NPART + 1) + pp];
    int lo = Bs[row * (NPART + 1) + pp + 1];
    uint32_t start = pse[row * (NPART + 1) + pp];
    if (threadIdx.x == 0) cnt = 0u;
    __syncthreads();
    const float* p = sc + row * NCOLS;
    for (int c = (int)threadIdx.x; c < NCOLS; c += (int)blockDim.x) {
        uint32_t u = orderable(p[c]);
        int b = (int)(u >> USHIFT);
        if (b > lo && b <= hi) {
            uint32_t pos = atomicAdd(&cnt, 1u);
            if (pos < (uint32_t)PARTCAP)
                lds[pos] = ((uint64_t)(~u) << 32) | (uint32_t)c;
        }
    }
    __syncthreads();
    uint32_t n = cnt;
    if (n > (uint32_t)PARTCAP) n = (uint32_t)PARTCAP;
    for (uint32_t i = n + threadIdx.x; i < (uint32_t)PARTCAP; i += blockDim.x)
        lds[i] = ~0ULL;
    __syncthreads();
    for (uint32_t k = 2; k <= (uint32_t)PARTCAP; k <<= 1) {
        for (uint32_t j = k >> 1; j > 0; j >>= 1) {
            for (uint32_t i = threadIdx.x; i < (uint32_t)PARTCAP; i += blockDim.x) {
                uint32_t ixj = i ^ j;
                if (ixj > i) {
                    uint64_t a = lds[i], bb = lds[ixj];
                    bool up = ((i & k) == 0);
                    if ((a > bb) == up) { lds[i] = bb; lds[ixj] = a; }
                }
            }
            __syncthreads();
        }
    }
    for (uint32_t i = threadIdx.x; i < n; i += blockDim.x) {
        uint32_t gpos = start + i;
        if (gpos < (uint32_t)MREF) {
            uint64_t key = lds[i];
            uint32_t u = ~(uint32_t)(key >> 32);
            rv[row * MREF + gpos] = unorderable(u);
            ri[row * MREF + gpos] = (uint32_t)(key & 0xFFFFFFFFu);
        }
    }
}

// R8-exact (1-col; the 4-col variant crashes the clang-22 frontend):
// nearest-ref mapping with float32 tie emulation.
__global__ void k_map(const float* __restrict__ sc, const float* __restrict__ rv,
                      const uint32_t* __restrict__ ri, int* __restrict__ out) {
    __shared__ float srv[MREF]; // 16 KiB
    int row = blockIdx.x >> 9;
    int col = ((blockIdx.x & 511) << 8) + threadIdx.x;
    const float* rvr = rv + row * MREF;
    for (int t = threadIdx.x; t < MREF; t += blockDim.x) srv[t] = rvr[t];
    __syncthreads();

    float s = sc[row * NCOLS + col];
    // first j with srv[j] <= s (srv descending)
    int lo = 0, hi = MREF;
    while (lo < hi) { int mid = (lo + hi) >> 1; if (srv[mid] <= s) hi = mid; else lo = mid + 1; }
    int p = lo, jmin;
    if (p == 0) jmin = 0;
    else if (p == MREF) jmin = MREF - 1;
    else {
        float dp = fabsf(s - srv[p]);
        float dm = fabsf(s - srv[p - 1]);
        jmin = (dm <= dp) ? (p - 1) : p; // tie -> smaller j (argmax-first)
    }
    float pmax = -fabsf(s - srv[jmin]);
    int jans = jmin;
    // exp-level tie merge: exp(pw - pmax) rounds to 1.0f => equal softmax prob,
    // argmax picks the smallest such j; winner set is contiguous.
    for (int j = jmin - 1; j >= 0; --j) {
        float pw = -fabsf(s - srv[j]);
        if (expf(pw - pmax) == 1.0f) jans = j; else break;
    }
    out[row * NCOLS + col] = (int)ri[row * MREF + jans];
}

extern "C" void kernel_launch(void* const* d_in, const int* in_sizes, int n_in,
                              void* d_out, int out_size, void* d_ws, size_t ws_size,
                              hipStream_t stream) {
    const float* sc = (const float*)d_in[0];
    int* out = (int*)d_out;
    char* w = (char*)d_ws;

    // ws layout (bytes):
    //   hslot [4*8*8192 u32] @ 0        (1048576)  (fully written by k_hist)
    //   Hrow  [4 u32]        @ 1048576  (pad 128)
    //   Bs    [4*33 int]     @ 1048704  (528, pad 640)
    //   pse   [4*33 u32]     @ 1049344  (528, pad 640)
    //   rv    [4*4096 f32]   @ 1049984  (65536)
    //   ri    [4*4096 u32]   @ 1115520  (65536)  -> total 1181056
    uint32_t* hslot = (uint32_t*)w;
    uint32_t* Hrow  = (uint32_t*)(w + 1048576);
    int*      Bs    = (int*)     (w + 1048704);
    uint32_t* pse   = (uint32_t*)(w + 1049344);
    float*    rv    = (float*)   (w + 1049984);
    uint32_t* ri    = (uint32_t*)(w + 1115520);

    k_hist   <<<BROWS * HIST_BLK_PER_ROW, 256, 0, stream>>>(sc, hslot);
    k_thresh <<<BROWS, 256, 0, stream>>>(hslot, Hrow, Bs, pse);
    k_psort  <<<BROWS * NPART, 512, 0, stream>>>(sc, Bs, pse, rv, ri);
    k_map    <<<BROWS * 512, 256, 0, stream>>>(sc, rv, ri, out);
}

// Round 10
// 84.957 us; speedup vs baseline: 1.5144x; 1.5144x over previous
//
#include <hip/hip_runtime.h>
#include <stdint.h>

// Problem constants (fixed by reference: scores (4, 131072) f32, m=4096, tau=1)
#define BROWS 4
#define NCOLS 131072           // 2^17
#define MREF  4096
#define HIST_BITS 13
#define NBUCK (1 << HIST_BITS) // 8192
#define USHIFT (32 - HIST_BITS)
#define CAP 6144               // candidates per row (<= 4095 + threshold-bucket count)
#define HIST_BLK_PER_ROW 8
#define NPART 32
#define PQUOTA 192             // quota spacing (R8-proven: max partition < 1024)
#define PARTCAP 1024           // fixed bitonic size

__device__ __forceinline__ uint32_t orderable(float f) {
    uint32_t u = __float_as_uint(f);
    return (u & 0x80000000u) ? ~u : (u | 0x80000000u);
}
__device__ __forceinline__ float unorderable(uint32_t u) {
    uint32_t b = (u & 0x80000000u) ? (u & 0x7FFFFFFFu) : ~u;
    return __uint_as_float(b);
}

// Per-block private histograms, plain-stored to slots (no zeroing kernel, no
// global atomics). 8 blocks/row over 16384-element chunks. (R9-proven)
__global__ void k_hist(const float* __restrict__ sc, uint32_t* __restrict__ hslot) {
    __shared__ uint32_t h[NBUCK]; // 32 KiB
    for (int t = threadIdx.x; t < NBUCK; t += blockDim.x) h[t] = 0u;
    __syncthreads();
    int row  = blockIdx.x / HIST_BLK_PER_ROW;
    int part = blockIdx.x % HIST_BLK_PER_ROW;
    const int CHUNK = NCOLS / HIST_BLK_PER_ROW; // 16384
    const float* p = sc + row * NCOLS + part * CHUNK;
    for (int c = threadIdx.x; c < CHUNK; c += blockDim.x) {
        uint32_t u = orderable(p[c]);
        atomicAdd(&h[u >> USHIFT], 1u);
    }
    __syncthreads();
    uint32_t* g = hslot + ((size_t)(row * HIST_BLK_PER_ROW + part)) * NBUCK;
    for (int t = threadIdx.x; t < NBUCK; t += blockDim.x) g[t] = h[t];
}

// One block per row: sum 8 slots into LDS hist (R9-proven), then the R8-proven
// presum + thread-0 quota walk. Emits Bs (R8 layout, NPART entries), pcur and
// pse for the compact/psort pair.
__global__ void k_thresh(const uint32_t* __restrict__ hslot, uint32_t* __restrict__ Hrow,
                         int* __restrict__ Bs, uint32_t* __restrict__ pcur,
                         uint32_t* __restrict__ pse) {
    __shared__ uint32_t h[NBUCK]; // 32 KiB summed histogram
    __shared__ uint32_t part[256];
    int row = blockIdx.x;
    const uint32_t* basep = hslot + (size_t)row * HIST_BLK_PER_ROW * NBUCK;
    for (int t = threadIdx.x; t < NBUCK; t += blockDim.x) {
        uint32_t s = 0;
        for (int sl = 0; sl < HIST_BLK_PER_ROW; ++sl) s += basep[sl * NBUCK + t];
        h[t] = s;
    }
    __syncthreads();
    int bhi = NBUCK - 1 - (int)threadIdx.x * 32;
    uint32_t run = 0;
    for (int k = 0; k < 32; ++k) run += h[bhi - k];
    part[threadIdx.x] = run;
    __syncthreads();
    if (threadIdx.x == 0) {
        int      Bloc[NPART];
        uint32_t Ploc[NPART];
        for (int p = 0; p < NPART; ++p) { Bloc[p] = -1; Ploc[p] = 0u; }
        uint32_t cum = 0, T = 0;
        int H = 0, pi = 1;
        bool done = false;
        for (int t = 0; t < 256 && !done; ++t) {
            uint32_t cafter = cum + part[t];
            bool cross = (cafter >= (uint32_t)MREF) ||
                         (pi < NPART && cafter >= (uint32_t)(pi * PQUOTA));
            if (cross) {
                int tp = NBUCK - 1 - t * 32;
                for (int k2 = 0; k2 < 32 && !done; ++k2) {
                    int b = tp - k2;
                    uint32_t prev = cum;
                    cum += h[b];
                    while (pi < NPART && cum >= (uint32_t)(pi * PQUOTA)) {
                        Bloc[pi] = b; Ploc[pi] = prev; ++pi;
                    }
                    if (cum >= (uint32_t)MREF) { H = b; T = cum; done = true; }
                }
            } else {
                cum = cafter;
            }
        }
        for (int p = pi; p < NPART; ++p) { Bloc[p] = H - 1; Ploc[p] = T; }
        if (T > (uint32_t)CAP) T = (uint32_t)CAP;
        Hrow[row] = (uint32_t)H;
        Bs[row * NPART + 0] = NBUCK; // sentinel, unused in membership test
        for (int p = 1; p < NPART; ++p) Bs[row * NPART + p] = Bloc[p];
        for (int p = 0; p < NPART; ++p) {
            uint32_t st = Ploc[p];
            if (st > (uint32_t)CAP) st = (uint32_t)CAP;
            pcur[row * NPART + p] = st;
            pse[row * (NPART + 1) + p] = st;
        }
        pse[row * (NPART + 1) + NPART] = T;
    }
}

// R8-exact: per-partition LDS counts + NPART global reserves, scatter to cand.
__global__ void k_compact(const float* __restrict__ sc, const uint32_t* __restrict__ Hrow,
                          const int* __restrict__ Bs, uint32_t* __restrict__ pcur,
                          uint64_t* __restrict__ cand) {
    __shared__ int bsL[NPART];
    __shared__ uint32_t cntP[NPART];
    __shared__ uint32_t baseP[NPART];
    int row = blockIdx.x >> 7;
    int base = (blockIdx.x & 127) << 10;
    uint32_t H = Hrow[row];
    if (threadIdx.x < NPART) {
        bsL[threadIdx.x] = Bs[row * NPART + threadIdx.x];
        cntP[threadIdx.x] = 0u;
    }
    __syncthreads();
    const float* p = sc + row * NCOLS + base;

    uint32_t myu[4], mycol[4], myr[4];
    int myp[4];
    uint32_t n = 0;
    for (int k = 0; k < 4; ++k) {
        int c = (int)threadIdx.x + (k << 8);
        uint32_t u = orderable(p[c]);
        uint32_t b = u >> USHIFT;
        if (b >= H) {
            int pp = 0;
            for (int q = 1; q < NPART; ++q) pp += ((int)b <= bsL[q]) ? 1 : 0;
            myu[n] = u; mycol[n] = (uint32_t)(base + c); myp[n] = pp;
            myr[n] = atomicAdd(&cntP[pp], 1u);
            ++n;
        }
    }
    __syncthreads();
    if (threadIdx.x < NPART)
        baseP[threadIdx.x] = atomicAdd(&pcur[row * NPART + threadIdx.x], cntP[threadIdx.x]);
    __syncthreads();
    uint64_t* cr = cand + (size_t)row * CAP;
    for (uint32_t k = 0; k < n; ++k) {
        uint32_t idx = baseP[myp[k]] + myr[k];
        if (idx < (uint32_t)CAP)
            cr[idx] = ((uint64_t)(~myu[k]) << 32) | mycol[k];
    }
}

// R8-exact: 128 blocks = 4 rows x 32 partitions, fixed P=1024 bitonic each.
__global__ void k_psort(const uint32_t* __restrict__ pse, uint64_t* __restrict__ cand,
                        float* __restrict__ rv, uint32_t* __restrict__ ri) {
    __shared__ uint64_t lds[PARTCAP]; // 8 KiB
    int row = blockIdx.x >> 5;
    int pp  = blockIdx.x & 31;
    uint32_t start = pse[row * (NPART + 1) + pp];
    uint32_t end   = pse[row * (NPART + 1) + pp + 1];
    if (end > (uint32_t)CAP) end = (uint32_t)CAP;
    uint32_t n = (end > start) ? (end - start) : 0u;
    if (n > (uint32_t)PARTCAP) n = (uint32_t)PARTCAP;
    uint64_t* seg = cand + (size_t)row * CAP + start;
    for (uint32_t i = threadIdx.x; i < (uint32_t)PARTCAP; i += blockDim.x)
        lds[i] = (i < n) ? seg[i] : ~0ULL;
    __syncthreads();
    for (uint32_t k = 2; k <= (uint32_t)PARTCAP; k <<= 1) {
        for (uint32_t j = k >> 1; j > 0; j >>= 1) {
            for (uint32_t i = threadIdx.x; i < (uint32_t)PARTCAP; i += blockDim.x) {
                uint32_t ixj = i ^ j;
                if (ixj > i) {
                    uint64_t a = lds[i], bb = lds[ixj];
                    bool up = ((i & k) == 0);
                    if ((a > bb) == up) { lds[i] = bb; lds[ixj] = a; }
                }
            }
            __syncthreads();
        }
    }
    for (uint32_t i = threadIdx.x; i < n; i += blockDim.x) {
        uint32_t gpos = start + i;
        if (gpos < (uint32_t)MREF) {
            uint64_t key = lds[i];
            uint32_t u = ~(uint32_t)(key >> 32);
            rv[row * MREF + gpos] = unorderable(u);
            ri[row * MREF + gpos] = (uint32_t)(key & 0xFFFFFFFFu);
        }
    }
}

// Nearest-ref mapping with float32 tie emulation. Per-thread code is R8-exact
// (1 col/thread; the 4-col inner-loop variant crashes the clang-22 frontend).
// Consolidated: 1024-thread blocks, 128 blocks/row -> 4x less srv staging.
__global__ void k_map(const float* __restrict__ sc, const float* __restrict__ rv,
                      const uint32_t* __restrict__ ri, int* __restrict__ out) {
    __shared__ float srv[MREF]; // 16 KiB
    int row = blockIdx.x >> 7;
    int col = ((blockIdx.x & 127) << 10) + threadIdx.x;
    const float* rvr = rv + row * MREF;
    for (int t = threadIdx.x; t < MREF; t += blockDim.x) srv[t] = rvr[t];
    __syncthreads();

    float s = sc[row * NCOLS + col];
    // first j with srv[j] <= s (srv descending)
    int lo = 0, hi = MREF;
    while (lo < hi) { int mid = (lo + hi) >> 1; if (srv[mid] <= s) hi = mid; else lo = mid + 1; }
    int p = lo, jmin;
    if (p == 0) jmin = 0;
    else if (p == MREF) jmin = MREF - 1;
    else {
        float dp = fabsf(s - srv[p]);
        float dm = fabsf(s - srv[p - 1]);
        jmin = (dm <= dp) ? (p - 1) : p; // tie -> smaller j (argmax-first)
    }
    float pmax = -fabsf(s - srv[jmin]);
    int jans = jmin;
    // exp-level tie merge: exp(pw - pmax) rounds to 1.0f => equal softmax prob,
    // argmax picks the smallest such j; winner set is contiguous.
    for (int j = jmin - 1; j >= 0; --j) {
        float pw = -fabsf(s - srv[j]);
        if (expf(pw - pmax) == 1.0f) jans = j; else break;
    }
    out[row * NCOLS + col] = (int)ri[row * MREF + jans];
}

extern "C" void kernel_launch(void* const* d_in, const int* in_sizes, int n_in,
                              void* d_out, int out_size, void* d_ws, size_t ws_size,
                              hipStream_t stream) {
    const float* sc = (const float*)d_in[0];
    int* out = (int*)d_out;
    char* w = (char*)d_ws;

    // ws layout (bytes):
    //   hslot [4*8*8192 u32] @ 0        (1048576)  (fully written by k_hist)
    //   Hrow  [4 u32]        @ 1048576  (pad 128)
    //   Bs    [4*32 int]     @ 1048704  (512)
    //   pcur  [4*32 u32]     @ 1049216  (512)
    //   pse   [4*33 u32]     @ 1049728  (528, pad 640)
    //   cand  [4*6144 u64]   @ 1050368  (196608)
    //   rv    [4*4096 f32]   @ 1246976  (65536)
    //   ri    [4*4096 u32]   @ 1312512  (65536)  -> total 1378048
    uint32_t* hslot = (uint32_t*)w;
    uint32_t* Hrow  = (uint32_t*)(w + 1048576);
    int*      Bs    = (int*)     (w + 1048704);
    uint32_t* pcur  = (uint32_t*)(w + 1049216);
    uint32_t* pse   = (uint32_t*)(w + 1049728);
    uint64_t* cand  = (uint64_t*)(w + 1050368);
    float*    rv    = (float*)   (w + 1246976);
    uint32_t* ri    = (uint32_t*)(w + 1312512);

    k_hist   <<<BROWS * HIST_BLK_PER_ROW, 256, 0, stream>>>(sc, hslot);
    k_thresh <<<BROWS, 256, 0, stream>>>(hslot, Hrow, Bs, pcur, pse);
    k_compact<<<512, 256, 0, stream>>>(sc, Hrow, Bs, pcur, cand);
    k_psort  <<<BROWS * NPART, 512, 0, stream>>>(pse, cand, rv, ri);
    k_map    <<<BROWS * 128, 1024, 0, stream>>>(sc, rv, ri, out);
}

// Round 11
// 66.589 us; speedup vs baseline: 1.9321x; 1.2758x over previous
//
#include <hip/hip_runtime.h>
#include <stdint.h>

// Problem constants (fixed by reference: scores (4, 131072) f32, m=4096, tau=1)
#define BROWS 4
#define NCOLS 131072           // 2^17
#define MREF  4096
#define HIST_BITS 13
#define NBUCK (1 << HIST_BITS) // 8192
#define USHIFT (32 - HIST_BITS)
#define CAP 6144               // candidates per row (<= 4095 + threshold-bucket count)
#define HIST_BLK_PER_ROW 8
#define NPART 32
#define PQUOTA 192             // quota spacing (R8-proven: max partition < 1024)
#define PARTCAP 1024           // max bitonic size

__device__ __forceinline__ uint32_t orderable(float f) {
    uint32_t u = __float_as_uint(f);
    return (u & 0x80000000u) ? ~u : (u | 0x80000000u);
}
__device__ __forceinline__ float unorderable(uint32_t u) {
    uint32_t b = (u & 0x80000000u) ? (u & 0x7FFFFFFFu) : ~u;
    return __uint_as_float(b);
}

__global__ void k_zero(uint32_t* hist) {
    int i = blockIdx.x * blockDim.x + threadIdx.x;
    int tot = BROWS * NBUCK;
    for (; i < tot; i += gridDim.x * blockDim.x) hist[i] = 0u;
}

// R8-exact: LDS-privatized histogram, 8 blocks/row, atomic flush to global.
__global__ void k_hist(const float* __restrict__ sc, uint32_t* __restrict__ hist) {
    __shared__ uint32_t h[NBUCK]; // 32 KiB
    for (int t = threadIdx.x; t < NBUCK; t += blockDim.x) h[t] = 0u;
    __syncthreads();
    int row  = blockIdx.x / HIST_BLK_PER_ROW;
    int part = blockIdx.x % HIST_BLK_PER_ROW;
    const int CHUNK = NCOLS / HIST_BLK_PER_ROW; // 16384
    const float* p = sc + row * NCOLS + part * CHUNK;
    for (int c = threadIdx.x; c < CHUNK; c += blockDim.x) {
        uint32_t u = orderable(p[c]);
        atomicAdd(&h[u >> USHIFT], 1u);
    }
    __syncthreads();
    uint32_t* g = hist + (row << HIST_BITS);
    for (int t = threadIdx.x; t < NBUCK; t += blockDim.x) {
        uint32_t v = h[t];
        if (v) atomicAdd(&g[t], v);
    }
}

// One block per row. R8 semantics, but the quota walk is PARALLEL: after the
// proven LDS scan gives excl, each thread emits the quota crossings that fall
// inside its own 32 descending buckets (prev < p*Q <= cum, only while
// prev < MREF); the MREF-crossing thread writes Hrow/pse[32]/trailing fills.
__global__ void k_thresh(const uint32_t* __restrict__ hist, uint32_t* __restrict__ Hrow,
                         int* __restrict__ Bs, uint32_t* __restrict__ pcur,
                         uint32_t* __restrict__ pse) {
    __shared__ uint32_t inc[256];
    int row = blockIdx.x;
    const uint32_t* h = hist + (row << HIST_BITS);
    int bhi = NBUCK - 1 - (int)threadIdx.x * 32;
    uint32_t run = 0;
    for (int k = 0; k < 32; ++k) run += h[bhi - k];
    inc[threadIdx.x] = run;
    __syncthreads();
    for (int off = 1; off < 256; off <<= 1) {
        uint32_t v = (threadIdx.x >= (uint32_t)off) ? inc[threadIdx.x - off] : 0u;
        __syncthreads();
        inc[threadIdx.x] += v;
        __syncthreads();
    }
    uint32_t excl = inc[threadIdx.x] - run; // elements in buckets > bhi

    if (threadIdx.x == 0) {
        Bs[row * NPART + 0] = NBUCK; // sentinel, unused in membership test
        pcur[row * NPART + 0] = 0u;
        pse[row * (NPART + 1) + 0] = 0u;
    }

    uint32_t cum = excl;
    for (int k = 0; k < 32; ++k) {
        int b = bhi - k;
        uint32_t prev = cum;
        cum += h[b];
        if (prev < (uint32_t)MREF) {
            // quota crossings inside this bucket (same order as R8's while-loop)
            uint32_t plo = prev / PQUOTA + 1u;
            uint32_t phi = cum / PQUOTA;
            if (phi > (uint32_t)(NPART - 1)) phi = (uint32_t)(NPART - 1);
            for (uint32_t p = plo; p <= phi; ++p) {
                uint32_t st = prev; if (st > (uint32_t)CAP) st = (uint32_t)CAP;
                Bs[row * NPART + p] = b;
                pcur[row * NPART + p] = st;
                pse[row * (NPART + 1) + p] = st;
            }
            if (cum >= (uint32_t)MREF) {
                uint32_t T = cum; if (T > (uint32_t)CAP) T = (uint32_t)CAP;
                Hrow[row] = (uint32_t)b;
                pse[row * (NPART + 1) + NPART] = T;
                // trailing (uncrossed) quotas: p*Q > cum
                uint32_t pstart = cum / PQUOTA + 1u;
                for (uint32_t p = pstart; p < (uint32_t)NPART; ++p) {
                    Bs[row * NPART + p] = b - 1;
                    pcur[row * NPART + p] = T;
                    pse[row * (NPART + 1) + p] = T;
                }
            }
        }
    }
}

// R8-exact: per-partition LDS counts + NPART global reserves, scatter to cand.
__global__ void k_compact(const float* __restrict__ sc, const uint32_t* __restrict__ Hrow,
                          const int* __restrict__ Bs, uint32_t* __restrict__ pcur,
                          uint64_t* __restrict__ cand) {
    __shared__ int bsL[NPART];
    __shared__ uint32_t cntP[NPART];
    __shared__ uint32_t baseP[NPART];
    int row = blockIdx.x >> 7;
    int base = (blockIdx.x & 127) << 10;
    uint32_t H = Hrow[row];
    if (threadIdx.x < NPART) {
        bsL[threadIdx.x] = Bs[row * NPART + threadIdx.x];
        cntP[threadIdx.x] = 0u;
    }
    __syncthreads();
    const float* p = sc + row * NCOLS + base;

    uint32_t myu[4], mycol[4], myr[4];
    int myp[4];
    uint32_t n = 0;
    for (int k = 0; k < 4; ++k) {
        int c = (int)threadIdx.x + (k << 8);
        uint32_t u = orderable(p[c]);
        uint32_t b = u >> USHIFT;
        if (b >= H) {
            int pp = 0;
            for (int q = 1; q < NPART; ++q) pp += ((int)b <= bsL[q]) ? 1 : 0;
            myu[n] = u; mycol[n] = (uint32_t)(base + c); myp[n] = pp;
            myr[n] = atomicAdd(&cntP[pp], 1u);
            ++n;
        }
    }
    __syncthreads();
    if (threadIdx.x < NPART)
        baseP[threadIdx.x] = atomicAdd(&pcur[row * NPART + threadIdx.x], cntP[threadIdx.x]);
    __syncthreads();
    uint64_t* cr = cand + (size_t)row * CAP;
    for (uint32_t k = 0; k < n; ++k) {
        uint32_t idx = baseP[myp[k]] + myr[k];
        if (idx < (uint32_t)CAP)
            cr[idx] = ((uint64_t)(~myu[k]) << 32) | mycol[k];
    }
}

// R8 structure + block-uniform size branch: P=256/512/1024 bitonic (36/45/55
// barrier phases); n is uniform across the block so the branch is legal.
#define BITONIC_SORT(PP)                                                        \
    for (uint32_t i = threadIdx.x; i < (uint32_t)(PP); i += blockDim.x)         \
        lds[i] = (i < n) ? seg[i] : ~0ULL;                                      \
    __syncthreads();                                                            \
    for (uint32_t k = 2; k <= (uint32_t)(PP); k <<= 1) {                        \
        for (uint32_t j = k >> 1; j > 0; j >>= 1) {                             \
            for (uint32_t i = threadIdx.x; i < (uint32_t)(PP); i += blockDim.x) { \
                uint32_t ixj = i ^ j;                                           \
                if (ixj > i) {                                                  \
                    uint64_t a = lds[i], bb = lds[ixj];                         \
                    bool up = ((i & k) == 0);                                   \
                    if ((a > bb) == up) { lds[i] = bb; lds[ixj] = a; }          \
                }                                                               \
            }                                                                   \
            __syncthreads();                                                    \
        }                                                                       \
    }

__global__ void k_psort(const uint32_t* __restrict__ pse, uint64_t* __restrict__ cand,
                        float* __restrict__ rv, uint32_t* __restrict__ ri) {
    __shared__ uint64_t lds[PARTCAP]; // 8 KiB
    int row = blockIdx.x >> 5;
    int pp  = blockIdx.x & 31;
    uint32_t start = pse[row * (NPART + 1) + pp];
    uint32_t end   = pse[row * (NPART + 1) + pp + 1];
    if (end > (uint32_t)CAP) end = (uint32_t)CAP;
    uint32_t n = (end > start) ? (end - start) : 0u;
    if (n > (uint32_t)PARTCAP) n = (uint32_t)PARTCAP;
    uint64_t* seg = cand + (size_t)row * CAP + start;
    if (n <= 256u) {
        BITONIC_SORT(256)
    } else if (n <= 512u) {
        BITONIC_SORT(512)
    } else {
        BITONIC_SORT(1024)
    }
    for (uint32_t i = threadIdx.x; i < n; i += blockDim.x) {
        uint32_t gpos = start + i;
        if (gpos < (uint32_t)MREF) {
            uint64_t key = lds[i];
            uint32_t u = ~(uint32_t)(key >> 32);
            rv[row * MREF + gpos] = unorderable(u);
            ri[row * MREF + gpos] = (uint32_t)(key & 0xFFFFFFFFu);
        }
    }
}

// R8-exact (1 col/thread; 4-col inner-loop variant crashes the clang-22
// frontend): nearest-ref mapping with float32 tie emulation.
__global__ void k_map(const float* __restrict__ sc, const float* __restrict__ rv,
                      const uint32_t* __restrict__ ri, int* __restrict__ out) {
    __shared__ float srv[MREF]; // 16 KiB
    int row = blockIdx.x >> 9;
    int col = ((blockIdx.x & 511) << 8) + threadIdx.x;
    const float* rvr = rv + row * MREF;
    for (int t = threadIdx.x; t < MREF; t += blockDim.x) srv[t] = rvr[t];
    __syncthreads();

    float s = sc[row * NCOLS + col];
    // first j with srv[j] <= s (srv descending)
    int lo = 0, hi = MREF;
    while (lo < hi) { int mid = (lo + hi) >> 1; if (srv[mid] <= s) hi = mid; else lo = mid + 1; }
    int p = lo, jmin;
    if (p == 0) jmin = 0;
    else if (p == MREF) jmin = MREF - 1;
    else {
        float dp = fabsf(s - srv[p]);
        float dm = fabsf(s - srv[p - 1]);
        jmin = (dm <= dp) ? (p - 1) : p; // tie -> smaller j (argmax-first)
    }
    float pmax = -fabsf(s - srv[jmin]);
    int jans = jmin;
    // exp-level tie merge: exp(pw - pmax) rounds to 1.0f => equal softmax prob,
    // argmax picks the smallest such j; winner set is contiguous.
    for (int j = jmin - 1; j >= 0; --j) {
        float pw = -fabsf(s - srv[j]);
        if (expf(pw - pmax) == 1.0f) jans = j; else break;
    }
    out[row * NCOLS + col] = (int)ri[row * MREF + jans];
}

extern "C" void kernel_launch(void* const* d_in, const int* in_sizes, int n_in,
                              void* d_out, int out_size, void* d_ws, size_t ws_size,
                              hipStream_t stream) {
    const float* sc = (const float*)d_in[0];
    int* out = (int*)d_out;
    char* w = (char*)d_ws;

    // ws layout (bytes):
    //   hist [4*8192 u32] @ 0       (131072) <- k_zero
    //   Hrow [4 u32]      @ 131072  (pad 128)
    //   Bs   [4*32 int]   @ 131200  (512)
    //   pcur [4*32 u32]   @ 131712  (512)
    //   pse  [4*33 u32]   @ 132224  (528, pad 640)
    //   cand [4*6144 u64] @ 132864  (196608)
    //   rv   [4*4096 f32] @ 329472  (65536)
    //   ri   [4*4096 u32] @ 395008  (65536)  -> total 460544
    uint32_t* hist = (uint32_t*)w;
    uint32_t* Hrow = (uint32_t*)(w + 131072);
    int*      Bs   = (int*)     (w + 131200);
    uint32_t* pcur = (uint32_t*)(w + 131712);
    uint32_t* pse  = (uint32_t*)(w + 132224);
    uint64_t* cand = (uint64_t*)(w + 132864);
    float*    rv   = (float*)   (w + 329472);
    uint32_t* ri   = (uint32_t*)(w + 395008);

    k_zero   <<<64, 256, 0, stream>>>(hist);
    k_hist   <<<BROWS * HIST_BLK_PER_ROW, 256, 0, stream>>>(sc, hist);
    k_thresh <<<BROWS, 256, 0, stream>>>(hist, Hrow, Bs, pcur, pse);
    k_compact<<<512, 256, 0, stream>>>(sc, Hrow, Bs, pcur, cand);
    k_psort  <<<BROWS * NPART, 512, 0, stream>>>(pse, cand, rv, ri);
    k_map    <<<BROWS * 512, 256, 0, stream>>>(sc, rv, ri, out);
}